// Round 7
// baseline (204.381 us; speedup 1.0000x reference)
//
#include <hip/hip_runtime.h>

#define B 4
#define N 4096
#define M 4096
#define C 32
#define BN (B * N)
// Workspace: wP[BN] packed u64 argmax cells = 128 KiB total.

// Force a wave-uniform pointer into SGPRs (readfirstlane is definitionally
// uniform). Plain C++ loads through it let the compiler emit scalar loads /
// same-address vector loads with ITS OWN correct waitcnt handling — no asm.
__device__ __forceinline__ const float* uniform_ptr(const float* p) {
    unsigned long long u = (unsigned long long)p;
    unsigned int lo = __builtin_amdgcn_readfirstlane((unsigned int)u);
    unsigned int hi = __builtin_amdgcn_readfirstlane((unsigned int)(u >> 32));
    return (const float*)(((unsigned long long)hi << 32) | (unsigned long long)lo);
}

// Monotone float -> uint mapping: a < b  <=>  fkey(a) < fkey(b).
__device__ __forceinline__ unsigned int fkey(float f) {
    unsigned int u = __float_as_uint(f);
    return (u & 0x80000000u) ? ~u : (u | 0x80000000u);
}

// Grid: 1024 blocks = (cgrp 0..7 | ngrp 0..31 | b 0..3), 256 threads.
// Block covers n in [ngrp*128, ngrp*128+128) x m in [cgrp*512, cgrp*512+512).
// Wave wv scans m-chunk [cgrp*512 + wv*128, +128). Lane owns n-rows
// ngrp*128+lane and +64 (R=2 reuse: one y-row read feeds 64 FMAs).
__global__ __launch_bounds__(256, 3)
void nn_main(const float* __restrict__ x, const float* __restrict__ y,
             unsigned long long* __restrict__ wP) {
    __shared__ float sh[512];          // -0.5*||y_m||^2 for this block's 512 m
    __shared__ float sk[4][128];
    __shared__ int   si[4][128];

    const int tid  = threadIdx.x;
    const int lane = tid & 63;
    const int wv   = tid >> 6;
    const int bi   = blockIdx.x;
    const int cgrp = bi & 7;
    const int ngrp = (bi >> 3) & 31;
    const int b    = bi >> 8;

    const int mblk = cgrp * 512;

    // ---- block-local y^2 norms (redundant across ngrp: 0.8% extra MACs) ----
    for (int r = tid; r < 512; r += 256) {
        const float4* p = (const float4*)(y + ((size_t)b * M + mblk + r) * C);
        float s = 0.f;
        #pragma unroll
        for (int j = 0; j < 8; ++j) {
            float4 v = p[j];
            s = fmaf(v.x, v.x, s); s = fmaf(v.y, v.y, s);
            s = fmaf(v.z, v.z, s); s = fmaf(v.w, v.w, s);
        }
        sh[r] = -0.5f * s;
    }

    // ---- this lane's two x rows -> VGPRs ----
    const int n0 = ngrp * 128 + lane;
    const int n1 = n0 + 64;
    float xr0[C], xr1[C];
    {
        const float4* p0 = (const float4*)(x + ((size_t)b * N + n0) * C);
        const float4* p1 = (const float4*)(x + ((size_t)b * N + n1) * C);
        #pragma unroll
        for (int j = 0; j < 8; ++j) {
            float4 v = p0[j];
            xr0[4*j] = v.x; xr0[4*j+1] = v.y; xr0[4*j+2] = v.z; xr0[4*j+3] = v.w;
            float4 w = p1[j];
            xr1[4*j] = w.x; xr1[4*j+1] = w.y; xr1[4*j+2] = w.z; xr1[4*j+3] = w.w;
        }
    }
    __syncthreads();

    // ---- hot loop: 128 m-rows, y read via uniform pointer (no LDS) ----
    const int mbase = mblk + wv * 128;
    const float4* yu = (const float4*)uniform_ptr(y + ((size_t)b * M + mbase) * C);

    float best0 = -__builtin_inff(), best1 = -__builtin_inff();
    int bix0 = 0, bix1 = 0;

    for (int i = 0; i < 128; ++i) {
        const float4* row = yu + (size_t)i * 8;
        const float  h    = sh[wv * 128 + i];
        float a0 = 0.f, b0 = 0.f, c0 = 0.f, d0 = 0.f;
        float a1 = 0.f, b1 = 0.f, c1 = 0.f, d1 = 0.f;
        #pragma unroll
        for (int j = 0; j < 8; ++j) {
            const float4 v = row[j];
            a0 = fmaf(xr0[4*j+0], v.x, a0);
            b0 = fmaf(xr0[4*j+1], v.y, b0);
            c0 = fmaf(xr0[4*j+2], v.z, c0);
            d0 = fmaf(xr0[4*j+3], v.w, d0);
            a1 = fmaf(xr1[4*j+0], v.x, a1);
            b1 = fmaf(xr1[4*j+1], v.y, b1);
            c1 = fmaf(xr1[4*j+2], v.z, c1);
            d1 = fmaf(xr1[4*j+3], v.w, d1);
        }
        const float key0 = ((a0 + b0) + (c0 + d0)) + h;
        const float key1 = ((a1 + b1) + (c1 + d1)) + h;
        const int   m    = mbase + i;
        if (key0 > best0) { best0 = key0; bix0 = m; }   // strict >: first occurrence
        if (key1 > best1) { best1 = key1; bix1 = m; }
    }

    // ---- merge the block's 4 waves (same n-rows, different m-chunks) ----
    sk[wv][lane]      = best0;  si[wv][lane]      = bix0;
    sk[wv][64 + lane] = best1;  si[wv][64 + lane] = bix1;
    __syncthreads();
    if (tid < 128) {
        float k = sk[0][tid];
        int  ix = si[0][tid];
        #pragma unroll
        for (int w = 1; w < 4; ++w) {
            const float kk = sk[w][tid];
            const int   ii = si[w][tid];
            if (kk > k || (kk == k && ii < ix)) { k = kk; ix = ii; }
        }
        const int n = ngrp * 128 + tid;
        // Pack (key, ~index): atomicMax keeps max key; on equal keys the larger
        // ~index wins == the SMALLER index (argmax first-occurrence rule).
        const unsigned long long pk =
            ((unsigned long long)fkey(k) << 32) | (unsigned long long)(unsigned int)(~ix);
        atomicMax(&wP[(size_t)b * N + n], pk);
    }
}

// ---- unpack winner per row, gather y_c ----
__global__ __launch_bounds__(256)
void nn_combine(const unsigned long long* __restrict__ wP,
                const float* __restrict__ yc, float* __restrict__ out) {
    const int i = blockIdx.x * 256 + threadIdx.x;  // 0 .. BN-1
    const int b = i >> 12;                         // N = 4096
    const unsigned long long p = wP[i];
    const int bx = (int)(~(unsigned int)(p & 0xFFFFFFFFull));
    const float* src = yc + ((size_t)b * M + bx) * 3;
    out[(size_t)i * 3 + 0] = src[0];
    out[(size_t)i * 3 + 1] = src[1];
    out[(size_t)i * 3 + 2] = src[2];
}

extern "C" void kernel_launch(void* const* d_in, const int* in_sizes, int n_in,
                              void* d_out, int out_size, void* d_ws, size_t ws_size,
                              hipStream_t stream) {
    const float* x  = (const float*)d_in[0];
    const float* y  = (const float*)d_in[1];
    const float* yc = (const float*)d_in[2];
    float* out      = (float*)d_out;

    unsigned long long* wP = (unsigned long long*)d_ws;   // BN u64 = 128 KiB

    hipMemsetAsync(wP, 0, (size_t)BN * 8, stream);
    nn_main<<<1024, 256, 0, stream>>>(x, y, wP);
    nn_combine<<<BN / 256, 256, 0, stream>>>(wP, yc, out);
}